// Round 17
// baseline (239.444 us; speedup 1.0000x reference)
//
#include <hip/hip_runtime.h>
#include <hip/hip_bf16.h>
#include <hip/hip_fp16.h>

typedef __attribute__((ext_vector_type(8))) short bf16x8;
typedef __attribute__((ext_vector_type(8))) _Float16 f16x8;
typedef __attribute__((ext_vector_type(4))) float f32x4;

// ---------------- weight transforms -------------------------------------------
// w1 [64][3][3][3] f32 -> w1t [64][32] bf16 (k = ic*9+ky*3+kx, pad 27..31 = 0)
// w2 [128][64][3][3] f32 -> w2h [9][2][4][128][8] bf16 panels
__global__ void wt_xform_all(const float* __restrict__ w1, const float* __restrict__ w2,
                             __hip_bfloat16* __restrict__ w1t, __hip_bfloat16* __restrict__ w2h) {
    int i = blockIdx.x * 256 + threadIdx.x;
    if (i < 2048) {
        int oc = i >> 5, k = i & 31;
        w1t[i] = (k < 27) ? __float2bfloat16(w1[oc * 27 + k]) : __float2bfloat16(0.f);
        return;
    }
    int j = i - 2048;
    if (j < 9 * 2 * 4 * 128 * 8) {
        int e  = j & 7;
        int oc = (j >> 3) & 127;
        int c  = (j >> 10) & 3;
        int h  = (j >> 12) & 1;
        int kk = j >> 13;
        int ic = h * 32 + c * 8 + e;
        int ky = kk / 3, kx = kk - ky * 3;
        w2h[j] = __float2bfloat16(w2[(((size_t)oc * 64 + ic) * 3 + ky) * 3 + kx]);
    }
}

// ---------------- conv1 implicit-GEMM on MFMA + fused bias/relu/maxpool ---------
__global__ void __launch_bounds__(256, 2)
conv1_mfma(const float* __restrict__ in,
           const __hip_bfloat16* __restrict__ w1t,
           const float* __restrict__ bias,
           __hip_bfloat16* __restrict__ out,
           int Hin, int Win, int PH, int PW, int tilesX) {
    __shared__ unsigned short xs[3 * 324];   // [ic][18 rows][18 cols] bf16 bits
    int t = threadIdx.x;
    int tile = blockIdx.x;
    int tileY = tile / tilesX, tileX = tile - tileY * tilesX;
    int b = blockIdx.z;
    int y0 = tileY * 16, x0 = tileX * 16;

    const float* inb = in + (size_t)b * 3 * Hin * Win;
    for (int i = t; i < 972; i += 256) {
        int ic = i / 324, rem = i - ic * 324;
        int r = rem / 18, c = rem - r * 18;
        int gy = y0 + r, gx = x0 + c;
        float v = 0.f;
        if (gy < Hin && gx < Win) v = inb[((size_t)ic * Hin + gy) * Win + gx];
        __hip_bfloat16 hv = __float2bfloat16(v);
        xs[i] = *(unsigned short*)&hv;
    }
    __syncthreads();

    int lane = t & 63, wv = t >> 6;
    int l15 = lane & 15, l4 = lane >> 4;

    bf16x8 af[4];
#pragma unroll
    for (int m = 0; m < 4; ++m)
        af[m] = *(const bf16x8*)&w1t[((size_t)(m * 16 + l15)) * 32 + l4 * 8];

    int off0, off1, off2, off3, off4, off5, off6, off7;
    int ok0, ok1, ok2, ok3, ok4, ok5, ok6, ok7;
#define MKOFF(J) { int kk = l4 * 8 + J; int ic = kk / 9; int r9 = kk - ic * 9; \
                   int ky = r9 / 3; int kx = r9 - ky * 3; \
                   ok##J = (kk < 27); off##J = ok##J ? (ic * 324 + ky * 18 + kx) : 0; }
    MKOFF(0) MKOFF(1) MKOFF(2) MKOFF(3) MKOFF(4) MKOFF(5) MKOFF(6) MKOFF(7)
#undef MKOFF

    f32x4 acc[4][4];
#pragma unroll
    for (int m = 0; m < 4; ++m)
#pragma unroll
        for (int n = 0; n < 4; ++n) acc[m][n] = (f32x4)(0.f);

#pragma unroll
    for (int n = 0; n < 4; ++n) {
        int y = wv * 4 + n;
        int base = y * 18 + l15;
        bf16x8 bfr;
        bfr[0] = ok0 ? (short)xs[base + off0] : (short)0;
        bfr[1] = ok1 ? (short)xs[base + off1] : (short)0;
        bfr[2] = ok2 ? (short)xs[base + off2] : (short)0;
        bfr[3] = ok3 ? (short)xs[base + off3] : (short)0;
        bfr[4] = ok4 ? (short)xs[base + off4] : (short)0;
        bfr[5] = ok5 ? (short)xs[base + off5] : (short)0;
        bfr[6] = ok6 ? (short)xs[base + off6] : (short)0;
        bfr[7] = ok7 ? (short)xs[base + off7] : (short)0;
#pragma unroll
        for (int m = 0; m < 4; ++m)
            acc[m][n] = __builtin_amdgcn_mfma_f32_16x16x32_bf16(af[m], bfr, acc[m][n], 0, 0, 0);
    }

    int qx = tileX * 8 + (l15 >> 1);
    bool xok = ((lane & 1) == 0) && (qx < PW);
#pragma unroll
    for (int m = 0; m < 4; ++m) {
        int ocb = m * 16 + l4 * 4;
#pragma unroll
        for (int np = 0; np < 2; ++np) {
            int qy = tileY * 8 + wv * 2 + np;
            union { __hip_bfloat16 h[4]; uint2 v; } pk;
#pragma unroll
            for (int r = 0; r < 4; ++r) {
                float v = fmaxf(acc[m][2 * np][r], acc[m][2 * np + 1][r]);
                v = fmaxf(v, __shfl_xor(v, 1));
                pk.h[r] = __float2bfloat16(fmaxf(v + bias[ocb + r], 0.f));
            }
            if (xok && qy < PH)
                *(uint2*)&out[(((size_t)b * PH + qy) * PW + qx) * 64 + ocb] = pk.v;
        }
    }
}

// ---------------- conv2 implicit-GEMM: barrier-free K-loop + rolling A-prefetch --
// R16: unroll-1 killed the spill (95us, MfmaUtil 34%) but each phase still waits
// on its L2 A-loads. Depth-2 rolling prefetch: issue phase p+1's A-loads, compute
// phase p with regs loaded last iter. Reg budget: 64 acc + 16 af + 16 afn + 16
// bfv + addr ~= 120 < 128 cap. A-load latency overlaps 16 MFMA + 4 ds_read.
__global__ void __launch_bounds__(256, 4)
conv2_mfma(const __hip_bfloat16* __restrict__ xin,
           const __hip_bfloat16* __restrict__ w2h,
           const float* __restrict__ bias, __half* __restrict__ out,
           int H1, int W1, int PH, int PW, int tilesY) {
    __shared__ uint4 xl4[10 * 18 * 8];   // 23040 B input tile; reused as store buffer

    int t = threadIdx.x;
    int tile = blockIdx.x;
    int tileY = tile % tilesY, tileX = tile / tilesY;
    int b = blockIdx.z;
    int y0 = tileY * 8, x0 = tileX * 16;

    const __hip_bfloat16* xb = xin + (size_t)b * H1 * W1 * 64;
    for (int s = t; s < 1440; s += 256) {
        int pixel = s >> 3, si = s & 7;
        int row = pixel / 18, col = pixel - row * 18;
        int gy = y0 + row, gx = x0 + col;
        uint4 v = make_uint4(0, 0, 0, 0);
        if (gy < H1 && gx < W1)
            v = *(const uint4*)&xb[((size_t)gy * W1 + gx) * 64 + si * 8];
        xl4[(pixel << 3) | (si ^ (col & 7))] = v;
    }
    __syncthreads();

    int lane = t & 63;
    int wid = t >> 6;
    int wr = wid >> 1;
    int wc = wid & 1;
    int l15 = lane & 15, l4 = lane >> 4;

    f32x4 acc[4][4];
#pragma unroll
    for (int m = 0; m < 4; ++m)
#pragma unroll
        for (int n = 0; n < 4; ++n) acc[m][n] = (f32x4)(0.f);

    // per-thread A base: w2h[p][l4][oc][8], oc = wr*64 + m*16 + l15
    const __hip_bfloat16* abase = w2h + ((size_t)l4 * 128 + wr * 64 + l15) * 8;

    bf16x8 af[4];
#pragma unroll
    for (int m = 0; m < 4; ++m)
        af[m] = *(const bf16x8*)(abase + m * 128);

#pragma unroll 1
    for (int p = 0; p < 18; ++p) {
        // issue next phase's A-loads before this phase's compute
        bf16x8 afn[4];
        if (p < 17) {
#pragma unroll
            for (int m = 0; m < 4; ++m)
                afn[m] = *(const bf16x8*)(abase + (size_t)(p + 1) * 4096 + m * 128);
        }

        const int kk = p >> 1, h = p & 1;
        const int ky = kk / 3, kx = kk - ky * 3;
        const int col = l15 + kx;
        const int sidx = (h * 4 + l4) ^ (col & 7);

        bf16x8 bfv[4];
#pragma unroll
        for (int n = 0; n < 4; ++n) {
            int row = wc * 4 + n + ky;
            bfv[n] = *(const bf16x8*)&xl4[((row * 18 + col) << 3) | sidx];
        }
#pragma unroll
        for (int m = 0; m < 4; ++m)
#pragma unroll
            for (int n = 0; n < 4; ++n)
                acc[m][n] = __builtin_amdgcn_mfma_f32_16x16x32_bf16(
                    af[m], bfv[n], acc[m][n], 0, 0, 0);

        if (p < 17) {
#pragma unroll
            for (int m = 0; m < 4; ++m) af[m] = afn[m];
        }
    }

    __syncthreads();   // before reusing xl4 as the store buffer

    __half* plds = (__half*)xl4;
#pragma unroll
    for (int m = 0; m < 4; ++m) {
        int ocb = wr * 64 + m * 16 + l4 * 4;
#pragma unroll
        for (int np = 0; np < 2; ++np) {
            int qyl = wc * 2 + np;
#pragma unroll
            for (int r = 0; r < 4; ++r) {
                float v = fmaxf(acc[m][2 * np][r], acc[m][2 * np + 1][r]);
                v = fmaxf(v, __shfl_xor(v, 1));
                if ((lane & 1) == 0) {
                    float u = fmaxf(v + bias[ocb + r], 0.f);
                    plds[((ocb + r) * 4 + qyl) * 8 + (l15 >> 1)] = __float2half(u);
                }
            }
        }
    }
    __syncthreads();

    int qx0 = tileX * 8, qy0 = tileY * 4;
    for (int i = t; i < 512; i += 256) {
        int oc = i >> 2, qy = i & 3;
        int gqy = qy0 + qy;
        if (gqy < PH) {
            __half* dst = out + (((size_t)b * 128 + oc) * PH + gqy) * PW + qx0;
            const __half* src = &plds[i * 8];
            if (qx0 + 8 <= PW) {
                *(uint4*)dst = *(const uint4*)src;
            } else {
                for (int q = 0; q < 8 && qx0 + q < PW; ++q) dst[q] = src[q];
            }
        }
    }
}

// ---------------- dual depthwise xcorr on MFMA (shift-in-M formulation) ----------
__global__ void __launch_bounds__(256, 4)
xcorr_mfma(const __half* __restrict__ x, const __half* __restrict__ k1,
           const __half* __restrict__ k2,
           float* __restrict__ out1, float* __restrict__ out2) {
    // 4 copies x 8704 B (64 rows x 68 f16, pitch 136 B) at stride 8720 (+16 skew)
    // + klds [2][14][16] f16 (896 B) at 34880. Total 35776 B.
    __shared__ __align__(16) char smem[35776];
    int bc = blockIdx.x, t = threadIdx.x;

    unsigned* c0p = (unsigned*)smem;   // copy0, dword view, row pitch 34 dwords
    const unsigned* xp = (const unsigned*)(x + (size_t)bc * 3844);   // 62x31 dwords
    for (int idx = t; idx < 64 * 34; idx += 256) {
        int r = idx / 34, i = idx - r * 34;
        unsigned v = 0;
        if (r < 62 && i < 31) v = xp[r * 31 + i];
        c0p[r * 34 + i] = v;
    }
    __half* kl = (__half*)(smem + 34880);
    if (t < 224) ((unsigned*)kl)[t] = 0;       // zero incl. kx=14,15 pad
    __syncthreads();

    // kernels -> klds [j][row][16]  (392 items, 256 threads -> strided loop)
    for (int idx = t; idx < 392; idx += 256) {
        int j = idx / 196, r196 = idx - j * 196;
        int kr = r196 / 14, kc = r196 - kr * 14;
        const __half* kg = (j == 0 ? k1 : k2) + (size_t)bc * 196;
        kl[(j * 14 + kr) * 16 + kc] = kg[r196];
    }
    // derive parity copies 1..3 from copy0
    for (int idx = t; idx < 64 * 34; idx += 256) {
        int r = idx / 34, i = idx - r * 34;
        unsigned d0 = c0p[r * 34 + i];
        unsigned d1 = (i < 33) ? c0p[r * 34 + i + 1] : 0u;
        unsigned d2 = (i < 32) ? c0p[r * 34 + i + 2] : 0u;
        int ro = r * 136 + i * 4;
        *(unsigned*)(smem +  8720 + ro) = (d0 >> 16) | (d1 << 16);
        *(unsigned*)(smem + 17440 + ro) = d1;
        *(unsigned*)(smem + 26160 + ro) = (d1 >> 16) | (d2 << 16);
    }
    __syncthreads();

    int lane = t & 63, wid = t >> 6;
    int l15 = lane & 15, l4 = lane >> 4;

    // A fragments: lane's A-row m = l15 -> (j = m>>3, s = m&7); k-slice l4*8+j'
    // -> ky = 2kp + (l4>>1), kx = (l4&1)*8 + j'
    int jm = l15 >> 3, sm = l15 & 7;
    f16x8 zf = (f16x8)(_Float16)0;
    f16x8 af[11];
#pragma unroll
    for (int kp = 0; kp < 11; ++kp) {
        int ky = 2 * kp + (l4 >> 1);
        int rr = ky - sm;
        int rc = min(max(rr, 0), 13);
        f16x8 v = *(const f16x8*)&kl[(jm * 14 + rc) * 16 + (l4 & 1) * 8];
        af[kp] = (rr >= 0 && rr < 14) ? v : zf;
    }

    int cbase = (l4 & 1) * 8 + l15;   // column offset from px0
    int rhalf = l4 >> 1;

    for (int tt = wid; tt < 28; tt += 4) {
        int u = tt % 7, q = tt / 7;
        int py0 = (u < 6) ? u * 8 : 41;
        int px0 = (q < 2) ? q * 16 : (q == 2 ? 32 : 33);

        int c0 = px0 + cbase;
        int p = c0 & 3;
        const char* baddr = smem + p * 8720 + (py0 + rhalf) * 136 + ((c0 - p) >> 2) * 8;

        f32x4 acc = (f32x4)(0.f);
#pragma unroll
        for (int kp = 0; kp < 11; ++kp) {
            union { uint2 u2[2]; f16x8 v; } bu;
            bu.u2[0] = *(const uint2*)(baddr + kp * 272);
            bu.u2[1] = *(const uint2*)(baddr + kp * 272 + 8);
            acc = __builtin_amdgcn_mfma_f32_16x16x32_f16(af[kp], bu.v, acc, 0, 0, 0);
        }

        // C: col = l15 (px), row = l4*4 + r -> (j = row>>3, s = row&7)
        int px = px0 + l15;
#pragma unroll
        for (int r = 0; r < 4; ++r) {
            int m = l4 * 4 + r;
            float* ob = (m >> 3) ? out2 : out1;
            ob[(size_t)bc * 2401 + (size_t)(py0 + (m & 7)) * 49 + px] = acc[r];
        }
    }
}

extern "C" void kernel_launch(void* const* d_in, const int* in_sizes, int n_in,
                              void* d_out, int out_size, void* d_ws, size_t ws_size,
                              hipStream_t stream) {
    const float* img = (const float*)d_in[0];
    const float* t1  = (const float*)d_in[1];
    const float* t2  = (const float*)d_in[2];
    const float* w1  = (const float*)d_in[3];
    const float* b1  = (const float*)d_in[4];
    const float* w2  = (const float*)d_in[5];
    const float* b2  = (const float*)d_in[6];
    float* out = (float*)d_out;

    char* ws = (char*)d_ws;
    __hip_bfloat16* bufA = (__hip_bfloat16*)ws;                 // 66,064,384 B
    __hip_bfloat16* w1t  = (__hip_bfloat16*)(ws + 66064384);    // 4,096 B
    __hip_bfloat16* w2h  = (__hip_bfloat16*)(ws + 66068480);    // 147,456 B
    __half* xf = (__half*)(ws + 66215936);                      // 31,490,048
    __half* k1 = (__half*)(ws + 97705984);                      // 1,605,632
    __half* k2 = (__half*)(ws + 99311616);                      // end 100,917,248

    wt_xform_all<<<296, 256, 0, stream>>>(w1, w2, w1t, w2h);

    conv1_mfma<<<dim3(256, 1, 32), 256, 0, stream>>>(img, w1t, b1, bufA,
                                                     256, 256, 127, 127, 16);
    conv2_mfma<<<dim3(128, 1, 32), 256, 0, stream>>>(bufA, w2h, b2, xf,
                                                     127, 127, 62, 62, 16);

    conv1_mfma<<<dim3(16, 1, 32), 256, 0, stream>>>(t1, w1t, b1, bufA,
                                                    64, 64, 31, 31, 4);
    conv2_mfma<<<dim3(8, 1, 32), 256, 0, stream>>>(bufA, w2h, b2, k1,
                                                   31, 31, 14, 14, 4);
    conv1_mfma<<<dim3(16, 1, 32), 256, 0, stream>>>(t2, w1t, b1, bufA,
                                                    64, 64, 31, 31, 4);
    conv2_mfma<<<dim3(8, 1, 32), 256, 0, stream>>>(bufA, w2h, b2, k2,
                                                   31, 31, 14, 14, 4);

    xcorr_mfma<<<4096, 256, 0, stream>>>(xf, k1, k2, out, out + (size_t)9834496);
}

// Round 18
// 238.118 us; speedup vs baseline: 1.0056x; 1.0056x over previous
//
#include <hip/hip_runtime.h>
#include <hip/hip_bf16.h>
#include <hip/hip_fp16.h>

typedef __attribute__((ext_vector_type(8))) short bf16x8;
typedef __attribute__((ext_vector_type(8))) _Float16 f16x8;
typedef __attribute__((ext_vector_type(4))) float f32x4;

// ---------------- weight transforms -------------------------------------------
// w1 [64][3][3][3] f32 -> w1t [64][32] bf16 (k = ic*9+ky*3+kx, pad 27..31 = 0)
// w2 [128][64][3][3] f32 -> w2h [9][2][4][128][8] bf16 panels
__global__ void wt_xform_all(const float* __restrict__ w1, const float* __restrict__ w2,
                             __hip_bfloat16* __restrict__ w1t, __hip_bfloat16* __restrict__ w2h) {
    int i = blockIdx.x * 256 + threadIdx.x;
    if (i < 2048) {
        int oc = i >> 5, k = i & 31;
        w1t[i] = (k < 27) ? __float2bfloat16(w1[oc * 27 + k]) : __float2bfloat16(0.f);
        return;
    }
    int j = i - 2048;
    if (j < 9 * 2 * 4 * 128 * 8) {
        int e  = j & 7;
        int oc = (j >> 3) & 127;
        int c  = (j >> 10) & 3;
        int h  = (j >> 12) & 1;
        int kk = j >> 13;
        int ic = h * 32 + c * 8 + e;
        int ky = kk / 3, kx = kk - ky * 3;
        w2h[j] = __float2bfloat16(w2[(((size_t)oc * 64 + ic) * 3 + ky) * 3 + kx]);
    }
}

// ---------------- conv1 implicit-GEMM on MFMA + fused bias/relu/maxpool ---------
__global__ void __launch_bounds__(256, 2)
conv1_mfma(const float* __restrict__ in,
           const __hip_bfloat16* __restrict__ w1t,
           const float* __restrict__ bias,
           __hip_bfloat16* __restrict__ out,
           int Hin, int Win, int PH, int PW, int tilesX) {
    __shared__ unsigned short xs[3 * 324];   // [ic][18 rows][18 cols] bf16 bits
    int t = threadIdx.x;
    int tile = blockIdx.x;
    int tileY = tile / tilesX, tileX = tile - tileY * tilesX;
    int b = blockIdx.z;
    int y0 = tileY * 16, x0 = tileX * 16;

    const float* inb = in + (size_t)b * 3 * Hin * Win;
    for (int i = t; i < 972; i += 256) {
        int ic = i / 324, rem = i - ic * 324;
        int r = rem / 18, c = rem - r * 18;
        int gy = y0 + r, gx = x0 + c;
        float v = 0.f;
        if (gy < Hin && gx < Win) v = inb[((size_t)ic * Hin + gy) * Win + gx];
        __hip_bfloat16 hv = __float2bfloat16(v);
        xs[i] = *(unsigned short*)&hv;
    }
    __syncthreads();

    int lane = t & 63, wv = t >> 6;
    int l15 = lane & 15, l4 = lane >> 4;

    bf16x8 af[4];
#pragma unroll
    for (int m = 0; m < 4; ++m)
        af[m] = *(const bf16x8*)&w1t[((size_t)(m * 16 + l15)) * 32 + l4 * 8];

    int off0, off1, off2, off3, off4, off5, off6, off7;
    int ok0, ok1, ok2, ok3, ok4, ok5, ok6, ok7;
#define MKOFF(J) { int kk = l4 * 8 + J; int ic = kk / 9; int r9 = kk - ic * 9; \
                   int ky = r9 / 3; int kx = r9 - ky * 3; \
                   ok##J = (kk < 27); off##J = ok##J ? (ic * 324 + ky * 18 + kx) : 0; }
    MKOFF(0) MKOFF(1) MKOFF(2) MKOFF(3) MKOFF(4) MKOFF(5) MKOFF(6) MKOFF(7)
#undef MKOFF

    f32x4 acc[4][4];
#pragma unroll
    for (int m = 0; m < 4; ++m)
#pragma unroll
        for (int n = 0; n < 4; ++n) acc[m][n] = (f32x4)(0.f);

#pragma unroll
    for (int n = 0; n < 4; ++n) {
        int y = wv * 4 + n;
        int base = y * 18 + l15;
        bf16x8 bfr;
        bfr[0] = ok0 ? (short)xs[base + off0] : (short)0;
        bfr[1] = ok1 ? (short)xs[base + off1] : (short)0;
        bfr[2] = ok2 ? (short)xs[base + off2] : (short)0;
        bfr[3] = ok3 ? (short)xs[base + off3] : (short)0;
        bfr[4] = ok4 ? (short)xs[base + off4] : (short)0;
        bfr[5] = ok5 ? (short)xs[base + off5] : (short)0;
        bfr[6] = ok6 ? (short)xs[base + off6] : (short)0;
        bfr[7] = ok7 ? (short)xs[base + off7] : (short)0;
#pragma unroll
        for (int m = 0; m < 4; ++m)
            acc[m][n] = __builtin_amdgcn_mfma_f32_16x16x32_bf16(af[m], bfr, acc[m][n], 0, 0, 0);
    }

    int qx = tileX * 8 + (l15 >> 1);
    bool xok = ((lane & 1) == 0) && (qx < PW);
#pragma unroll
    for (int m = 0; m < 4; ++m) {
        int ocb = m * 16 + l4 * 4;
#pragma unroll
        for (int np = 0; np < 2; ++np) {
            int qy = tileY * 8 + wv * 2 + np;
            union { __hip_bfloat16 h[4]; uint2 v; } pk;
#pragma unroll
            for (int r = 0; r < 4; ++r) {
                float v = fmaxf(acc[m][2 * np][r], acc[m][2 * np + 1][r]);
                v = fmaxf(v, __shfl_xor(v, 1));
                pk.h[r] = __float2bfloat16(fmaxf(v + bias[ocb + r], 0.f));
            }
            if (xok && qy < PH)
                *(uint2*)&out[(((size_t)b * PH + qy) * PW + qx) * 64 + ocb] = pk.v;
        }
    }
}

// ---------------- conv2 implicit-GEMM: barrier-free, kk-merged 9-phase K-loop ----
// R17 lesson: cross-phase prefetch regs (afn held over MFMA block) cost occupancy
// (42->35%) and regressed. Instead merge both h-halves per kk: 9 phases, each
// {8 A-loads pipelined under ONE L2 latency -> 32 MFMA}. Loads issue-and-use
// within the phase (short lifetimes); half the stall events, 2x work per stall.
// launch_bounds(256,3): VGPR cap ~170 (need ~127: 64 acc + 32 af + 16 bfv).
__global__ void __launch_bounds__(256, 3)
conv2_mfma(const __hip_bfloat16* __restrict__ xin,
           const __hip_bfloat16* __restrict__ w2h,
           const float* __restrict__ bias, __half* __restrict__ out,
           int H1, int W1, int PH, int PW, int tilesY) {
    __shared__ uint4 xl4[10 * 18 * 8];   // 23040 B input tile; reused as store buffer

    int t = threadIdx.x;
    int tile = blockIdx.x;
    int tileY = tile % tilesY, tileX = tile / tilesY;
    int b = blockIdx.z;
    int y0 = tileY * 8, x0 = tileX * 16;

    const __hip_bfloat16* xb = xin + (size_t)b * H1 * W1 * 64;
    for (int s = t; s < 1440; s += 256) {
        int pixel = s >> 3, si = s & 7;
        int row = pixel / 18, col = pixel - row * 18;
        int gy = y0 + row, gx = x0 + col;
        uint4 v = make_uint4(0, 0, 0, 0);
        if (gy < H1 && gx < W1)
            v = *(const uint4*)&xb[((size_t)gy * W1 + gx) * 64 + si * 8];
        xl4[(pixel << 3) | (si ^ (col & 7))] = v;
    }
    __syncthreads();

    int lane = t & 63;
    int wid = t >> 6;
    int wr = wid >> 1;
    int wc = wid & 1;
    int l15 = lane & 15, l4 = lane >> 4;

    f32x4 acc[4][4];
#pragma unroll
    for (int m = 0; m < 4; ++m)
#pragma unroll
        for (int n = 0; n < 4; ++n) acc[m][n] = (f32x4)(0.f);

    // per-thread A base: w2h[p][l4][oc][8], oc = wr*64 + m*16 + l15
    const __hip_bfloat16* abase = w2h + ((size_t)l4 * 128 + wr * 64 + l15) * 8;

#pragma unroll 1
    for (int kk = 0; kk < 9; ++kk) {
        // 8 A-loads for both h-halves of this kk: one latency covers all
        bf16x8 af[8];
#pragma unroll
        for (int q = 0; q < 8; ++q)
            af[q] = *(const bf16x8*)(abase + (size_t)(kk * 2 + (q >> 2)) * 4096 + (q & 3) * 128);

        const int ky = kk / 3, kx = kk - ky * 3;
        const int col = l15 + kx;
        const int csw = col & 7;

#pragma unroll
        for (int h = 0; h < 2; ++h) {
            const int sidx = (h * 4 + l4) ^ csw;
            bf16x8 bfv[4];
#pragma unroll
            for (int n = 0; n < 4; ++n) {
                int row = wc * 4 + n + ky;
                bfv[n] = *(const bf16x8*)&xl4[((row * 18 + col) << 3) | sidx];
            }
#pragma unroll
            for (int m = 0; m < 4; ++m)
#pragma unroll
                for (int n = 0; n < 4; ++n)
                    acc[m][n] = __builtin_amdgcn_mfma_f32_16x16x32_bf16(
                        af[h * 4 + m], bfv[n], acc[m][n], 0, 0, 0);
        }
    }

    __syncthreads();   // before reusing xl4 as the store buffer

    __half* plds = (__half*)xl4;
#pragma unroll
    for (int m = 0; m < 4; ++m) {
        int ocb = wr * 64 + m * 16 + l4 * 4;
#pragma unroll
        for (int np = 0; np < 2; ++np) {
            int qyl = wc * 2 + np;
#pragma unroll
            for (int r = 0; r < 4; ++r) {
                float v = fmaxf(acc[m][2 * np][r], acc[m][2 * np + 1][r]);
                v = fmaxf(v, __shfl_xor(v, 1));
                if ((lane & 1) == 0) {
                    float u = fmaxf(v + bias[ocb + r], 0.f);
                    plds[((ocb + r) * 4 + qyl) * 8 + (l15 >> 1)] = __float2half(u);
                }
            }
        }
    }
    __syncthreads();

    int qx0 = tileX * 8, qy0 = tileY * 4;
    for (int i = t; i < 512; i += 256) {
        int oc = i >> 2, qy = i & 3;
        int gqy = qy0 + qy;
        if (gqy < PH) {
            __half* dst = out + (((size_t)b * 128 + oc) * PH + gqy) * PW + qx0;
            const __half* src = &plds[i * 8];
            if (qx0 + 8 <= PW) {
                *(uint4*)dst = *(const uint4*)src;
            } else {
                for (int q = 0; q < 8 && qx0 + q < PW; ++q) dst[q] = src[q];
            }
        }
    }
}

// ---------------- dual depthwise xcorr on MFMA (shift-in-M formulation) ----------
__global__ void __launch_bounds__(256, 4)
xcorr_mfma(const __half* __restrict__ x, const __half* __restrict__ k1,
           const __half* __restrict__ k2,
           float* __restrict__ out1, float* __restrict__ out2) {
    // 4 copies x 8704 B (64 rows x 68 f16, pitch 136 B) at stride 8720 (+16 skew)
    // + klds [2][14][16] f16 (896 B) at 34880. Total 35776 B.
    __shared__ __align__(16) char smem[35776];
    int bc = blockIdx.x, t = threadIdx.x;

    unsigned* c0p = (unsigned*)smem;   // copy0, dword view, row pitch 34 dwords
    const unsigned* xp = (const unsigned*)(x + (size_t)bc * 3844);   // 62x31 dwords
    for (int idx = t; idx < 64 * 34; idx += 256) {
        int r = idx / 34, i = idx - r * 34;
        unsigned v = 0;
        if (r < 62 && i < 31) v = xp[r * 31 + i];
        c0p[r * 34 + i] = v;
    }
    __half* kl = (__half*)(smem + 34880);
    if (t < 224) ((unsigned*)kl)[t] = 0;       // zero incl. kx=14,15 pad
    __syncthreads();

    // kernels -> klds [j][row][16]  (392 items, 256 threads -> strided loop)
    for (int idx = t; idx < 392; idx += 256) {
        int j = idx / 196, r196 = idx - j * 196;
        int kr = r196 / 14, kc = r196 - kr * 14;
        const __half* kg = (j == 0 ? k1 : k2) + (size_t)bc * 196;
        kl[(j * 14 + kr) * 16 + kc] = kg[r196];
    }
    // derive parity copies 1..3 from copy0
    for (int idx = t; idx < 64 * 34; idx += 256) {
        int r = idx / 34, i = idx - r * 34;
        unsigned d0 = c0p[r * 34 + i];
        unsigned d1 = (i < 33) ? c0p[r * 34 + i + 1] : 0u;
        unsigned d2 = (i < 32) ? c0p[r * 34 + i + 2] : 0u;
        int ro = r * 136 + i * 4;
        *(unsigned*)(smem +  8720 + ro) = (d0 >> 16) | (d1 << 16);
        *(unsigned*)(smem + 17440 + ro) = d1;
        *(unsigned*)(smem + 26160 + ro) = (d1 >> 16) | (d2 << 16);
    }
    __syncthreads();

    int lane = t & 63, wid = t >> 6;
    int l15 = lane & 15, l4 = lane >> 4;

    // A fragments: lane's A-row m = l15 -> (j = m>>3, s = m&7); k-slice l4*8+j'
    // -> ky = 2kp + (l4>>1), kx = (l4&1)*8 + j'
    int jm = l15 >> 3, sm = l15 & 7;
    f16x8 zf = (f16x8)(_Float16)0;
    f16x8 af[11];
#pragma unroll
    for (int kp = 0; kp < 11; ++kp) {
        int ky = 2 * kp + (l4 >> 1);
        int rr = ky - sm;
        int rc = min(max(rr, 0), 13);
        f16x8 v = *(const f16x8*)&kl[(jm * 14 + rc) * 16 + (l4 & 1) * 8];
        af[kp] = (rr >= 0 && rr < 14) ? v : zf;
    }

    int cbase = (l4 & 1) * 8 + l15;   // column offset from px0
    int rhalf = l4 >> 1;

    for (int tt = wid; tt < 28; tt += 4) {
        int u = tt % 7, q = tt / 7;
        int py0 = (u < 6) ? u * 8 : 41;
        int px0 = (q < 2) ? q * 16 : (q == 2 ? 32 : 33);

        int c0 = px0 + cbase;
        int p = c0 & 3;
        const char* baddr = smem + p * 8720 + (py0 + rhalf) * 136 + ((c0 - p) >> 2) * 8;

        f32x4 acc = (f32x4)(0.f);
#pragma unroll
        for (int kp = 0; kp < 11; ++kp) {
            union { uint2 u2[2]; f16x8 v; } bu;
            bu.u2[0] = *(const uint2*)(baddr + kp * 272);
            bu.u2[1] = *(const uint2*)(baddr + kp * 272 + 8);
            acc = __builtin_amdgcn_mfma_f32_16x16x32_f16(af[kp], bu.v, acc, 0, 0, 0);
        }

        // C: col = l15 (px), row = l4*4 + r -> (j = row>>3, s = row&7)
        int px = px0 + l15;
#pragma unroll
        for (int r = 0; r < 4; ++r) {
            int m = l4 * 4 + r;
            float* ob = (m >> 3) ? out2 : out1;
            ob[(size_t)bc * 2401 + (size_t)(py0 + (m & 7)) * 49 + px] = acc[r];
        }
    }
}

extern "C" void kernel_launch(void* const* d_in, const int* in_sizes, int n_in,
                              void* d_out, int out_size, void* d_ws, size_t ws_size,
                              hipStream_t stream) {
    const float* img = (const float*)d_in[0];
    const float* t1  = (const float*)d_in[1];
    const float* t2  = (const float*)d_in[2];
    const float* w1  = (const float*)d_in[3];
    const float* b1  = (const float*)d_in[4];
    const float* w2  = (const float*)d_in[5];
    const float* b2  = (const float*)d_in[6];
    float* out = (float*)d_out;

    char* ws = (char*)d_ws;
    __hip_bfloat16* bufA = (__hip_bfloat16*)ws;                 // 66,064,384 B
    __hip_bfloat16* w1t  = (__hip_bfloat16*)(ws + 66064384);    // 4,096 B
    __hip_bfloat16* w2h  = (__hip_bfloat16*)(ws + 66068480);    // 147,456 B
    __half* xf = (__half*)(ws + 66215936);                      // 31,490,048
    __half* k1 = (__half*)(ws + 97705984);                      // 1,605,632
    __half* k2 = (__half*)(ws + 99311616);                      // end 100,917,248

    wt_xform_all<<<296, 256, 0, stream>>>(w1, w2, w1t, w2h);

    conv1_mfma<<<dim3(256, 1, 32), 256, 0, stream>>>(img, w1t, b1, bufA,
                                                     256, 256, 127, 127, 16);
    conv2_mfma<<<dim3(128, 1, 32), 256, 0, stream>>>(bufA, w2h, b2, xf,
                                                     127, 127, 62, 62, 16);

    conv1_mfma<<<dim3(16, 1, 32), 256, 0, stream>>>(t1, w1t, b1, bufA,
                                                    64, 64, 31, 31, 4);
    conv2_mfma<<<dim3(8, 1, 32), 256, 0, stream>>>(bufA, w2h, b2, k1,
                                                   31, 31, 14, 14, 4);
    conv1_mfma<<<dim3(16, 1, 32), 256, 0, stream>>>(t2, w1t, b1, bufA,
                                                    64, 64, 31, 31, 4);
    conv2_mfma<<<dim3(8, 1, 32), 256, 0, stream>>>(bufA, w2h, b2, k2,
                                                   31, 31, 14, 14, 4);

    xcorr_mfma<<<4096, 256, 0, stream>>>(xf, k1, k2, out, out + (size_t)9834496);
}

// Round 19
// 221.067 us; speedup vs baseline: 1.0831x; 1.0771x over previous
//
#include <hip/hip_runtime.h>
#include <hip/hip_bf16.h>
#include <hip/hip_fp16.h>

typedef __attribute__((ext_vector_type(8))) short bf16x8;
typedef __attribute__((ext_vector_type(8))) _Float16 f16x8;
typedef __attribute__((ext_vector_type(4))) float f32x4;

// ---------------- weight transforms -------------------------------------------
// w1 [64][3][3][3] f32 -> w1t [64][32] bf16 (k = ic*9+ky*3+kx, pad 27..31 = 0)
// w2 [128][64][3][3] f32 -> w2h [9][2][4][128][8] bf16 panels
__global__ void wt_xform_all(const float* __restrict__ w1, const float* __restrict__ w2,
                             __hip_bfloat16* __restrict__ w1t, __hip_bfloat16* __restrict__ w2h) {
    int i = blockIdx.x * 256 + threadIdx.x;
    if (i < 2048) {
        int oc = i >> 5, k = i & 31;
        w1t[i] = (k < 27) ? __float2bfloat16(w1[oc * 27 + k]) : __float2bfloat16(0.f);
        return;
    }
    int j = i - 2048;
    if (j < 9 * 2 * 4 * 128 * 8) {
        int e  = j & 7;
        int oc = (j >> 3) & 127;
        int c  = (j >> 10) & 3;
        int h  = (j >> 12) & 1;
        int kk = j >> 13;
        int ic = h * 32 + c * 8 + e;
        int ky = kk / 3, kx = kk - ky * 3;
        w2h[j] = __float2bfloat16(w2[(((size_t)oc * 64 + ic) * 3 + ky) * 3 + kx]);
    }
}

// ---------------- conv1 implicit-GEMM on MFMA + fused bias/relu/maxpool ---------
// Dual-input: blockIdx.y selects (inA,outA) or (inB,outB) -> one launch covers
// both templates.
__global__ void __launch_bounds__(256, 2)
conv1_mfma(const float* __restrict__ inA, const float* __restrict__ inB,
           const __hip_bfloat16* __restrict__ w1t,
           const float* __restrict__ bias,
           __hip_bfloat16* __restrict__ outA, __hip_bfloat16* __restrict__ outB,
           int Hin, int Win, int PH, int PW, int tilesX) {
    __shared__ unsigned short xs[3 * 324];   // [ic][18 rows][18 cols] bf16 bits
    int t = threadIdx.x;
    int tile = blockIdx.x;
    int tileY = tile / tilesX, tileX = tile - tileY * tilesX;
    int b = blockIdx.z;
    const float* in = blockIdx.y ? inB : inA;
    __hip_bfloat16* out = blockIdx.y ? outB : outA;
    int y0 = tileY * 16, x0 = tileX * 16;

    const float* inb = in + (size_t)b * 3 * Hin * Win;
    for (int i = t; i < 972; i += 256) {
        int ic = i / 324, rem = i - ic * 324;
        int r = rem / 18, c = rem - r * 18;
        int gy = y0 + r, gx = x0 + c;
        float v = 0.f;
        if (gy < Hin && gx < Win) v = inb[((size_t)ic * Hin + gy) * Win + gx];
        __hip_bfloat16 hv = __float2bfloat16(v);
        xs[i] = *(unsigned short*)&hv;
    }
    __syncthreads();

    int lane = t & 63, wv = t >> 6;
    int l15 = lane & 15, l4 = lane >> 4;

    bf16x8 af[4];
#pragma unroll
    for (int m = 0; m < 4; ++m)
        af[m] = *(const bf16x8*)&w1t[((size_t)(m * 16 + l15)) * 32 + l4 * 8];

    int off0, off1, off2, off3, off4, off5, off6, off7;
    int ok0, ok1, ok2, ok3, ok4, ok5, ok6, ok7;
#define MKOFF(J) { int kk = l4 * 8 + J; int ic = kk / 9; int r9 = kk - ic * 9; \
                   int ky = r9 / 3; int kx = r9 - ky * 3; \
                   ok##J = (kk < 27); off##J = ok##J ? (ic * 324 + ky * 18 + kx) : 0; }
    MKOFF(0) MKOFF(1) MKOFF(2) MKOFF(3) MKOFF(4) MKOFF(5) MKOFF(6) MKOFF(7)
#undef MKOFF

    f32x4 acc[4][4];
#pragma unroll
    for (int m = 0; m < 4; ++m)
#pragma unroll
        for (int n = 0; n < 4; ++n) acc[m][n] = (f32x4)(0.f);

#pragma unroll
    for (int n = 0; n < 4; ++n) {
        int y = wv * 4 + n;
        int base = y * 18 + l15;
        bf16x8 bfr;
        bfr[0] = ok0 ? (short)xs[base + off0] : (short)0;
        bfr[1] = ok1 ? (short)xs[base + off1] : (short)0;
        bfr[2] = ok2 ? (short)xs[base + off2] : (short)0;
        bfr[3] = ok3 ? (short)xs[base + off3] : (short)0;
        bfr[4] = ok4 ? (short)xs[base + off4] : (short)0;
        bfr[5] = ok5 ? (short)xs[base + off5] : (short)0;
        bfr[6] = ok6 ? (short)xs[base + off6] : (short)0;
        bfr[7] = ok7 ? (short)xs[base + off7] : (short)0;
#pragma unroll
        for (int m = 0; m < 4; ++m)
            acc[m][n] = __builtin_amdgcn_mfma_f32_16x16x32_bf16(af[m], bfr, acc[m][n], 0, 0, 0);
    }

    int qx = tileX * 8 + (l15 >> 1);
    bool xok = ((lane & 1) == 0) && (qx < PW);
#pragma unroll
    for (int m = 0; m < 4; ++m) {
        int ocb = m * 16 + l4 * 4;
#pragma unroll
        for (int np = 0; np < 2; ++np) {
            int qy = tileY * 8 + wv * 2 + np;
            union { __hip_bfloat16 h[4]; uint2 v; } pk;
#pragma unroll
            for (int r = 0; r < 4; ++r) {
                float v = fmaxf(acc[m][2 * np][r], acc[m][2 * np + 1][r]);
                v = fmaxf(v, __shfl_xor(v, 1));
                pk.h[r] = __float2bfloat16(fmaxf(v + bias[ocb + r], 0.f));
            }
            if (xok && qy < PH)
                *(uint2*)&out[(((size_t)b * PH + qy) * PW + qx) * 64 + ocb] = pk.v;
        }
    }
}

// ---------------- conv2 implicit-GEMM: barrier-free K-loop, A direct from L2 -----
// R16 measured-best (95us): unroll-1, A-fragments loaded from L2 per phase,
// zero barriers in the K-loop. R17 (rolling prefetch) and R18 (kk-merge) both
// regressed -> reverted. Dual-input select by blockIdx.y for template merge.
__global__ void __launch_bounds__(256, 4)
conv2_mfma(const __hip_bfloat16* __restrict__ xinA, const __hip_bfloat16* __restrict__ xinB,
           const __hip_bfloat16* __restrict__ w2h,
           const float* __restrict__ bias,
           __half* __restrict__ outA, __half* __restrict__ outB,
           int H1, int W1, int PH, int PW, int tilesY) {
    __shared__ uint4 xl4[10 * 18 * 8];   // 23040 B input tile; reused as store buffer

    int t = threadIdx.x;
    int tile = blockIdx.x;
    int tileY = tile % tilesY, tileX = tile / tilesY;
    int b = blockIdx.z;
    const __hip_bfloat16* xin = blockIdx.y ? xinB : xinA;
    __half* out = blockIdx.y ? outB : outA;
    int y0 = tileY * 8, x0 = tileX * 16;

    const __hip_bfloat16* xb = xin + (size_t)b * H1 * W1 * 64;
    for (int s = t; s < 1440; s += 256) {
        int pixel = s >> 3, si = s & 7;
        int row = pixel / 18, col = pixel - row * 18;
        int gy = y0 + row, gx = x0 + col;
        uint4 v = make_uint4(0, 0, 0, 0);
        if (gy < H1 && gx < W1)
            v = *(const uint4*)&xb[((size_t)gy * W1 + gx) * 64 + si * 8];
        xl4[(pixel << 3) | (si ^ (col & 7))] = v;
    }
    __syncthreads();

    int lane = t & 63;
    int wid = t >> 6;
    int wr = wid >> 1;
    int wc = wid & 1;
    int l15 = lane & 15, l4 = lane >> 4;

    f32x4 acc[4][4];
#pragma unroll
    for (int m = 0; m < 4; ++m)
#pragma unroll
        for (int n = 0; n < 4; ++n) acc[m][n] = (f32x4)(0.f);

    // per-thread A base: w2h[p][l4][oc][8], oc = wr*64 + m*16 + l15
    const __hip_bfloat16* abase = w2h + ((size_t)l4 * 128 + wr * 64 + l15) * 8;

#pragma unroll 1
    for (int p = 0; p < 18; ++p) {
        const int kk = p >> 1, h = p & 1;
        const int ky = kk / 3, kx = kk - ky * 3;
        const int col = l15 + kx;
        const int sidx = (h * 4 + l4) ^ (col & 7);

        bf16x8 af[4], bfv[4];
#pragma unroll
        for (int m = 0; m < 4; ++m)
            af[m] = *(const bf16x8*)(abase + (size_t)p * 4096 + m * 128);
#pragma unroll
        for (int n = 0; n < 4; ++n) {
            int row = wc * 4 + n + ky;
            bfv[n] = *(const bf16x8*)&xl4[((row * 18 + col) << 3) | sidx];
        }
#pragma unroll
        for (int m = 0; m < 4; ++m)
#pragma unroll
            for (int n = 0; n < 4; ++n)
                acc[m][n] = __builtin_amdgcn_mfma_f32_16x16x32_bf16(
                    af[m], bfv[n], acc[m][n], 0, 0, 0);
    }

    __syncthreads();   // before reusing xl4 as the store buffer

    __half* plds = (__half*)xl4;
#pragma unroll
    for (int m = 0; m < 4; ++m) {
        int ocb = wr * 64 + m * 16 + l4 * 4;
#pragma unroll
        for (int np = 0; np < 2; ++np) {
            int qyl = wc * 2 + np;
#pragma unroll
            for (int r = 0; r < 4; ++r) {
                float v = fmaxf(acc[m][2 * np][r], acc[m][2 * np + 1][r]);
                v = fmaxf(v, __shfl_xor(v, 1));
                if ((lane & 1) == 0) {
                    float u = fmaxf(v + bias[ocb + r], 0.f);
                    plds[((ocb + r) * 4 + qyl) * 8 + (l15 >> 1)] = __float2half(u);
                }
            }
        }
    }
    __syncthreads();

    int qx0 = tileX * 8, qy0 = tileY * 4;
    for (int i = t; i < 512; i += 256) {
        int oc = i >> 2, qy = i & 3;
        int gqy = qy0 + qy;
        if (gqy < PH) {
            __half* dst = out + (((size_t)b * 128 + oc) * PH + gqy) * PW + qx0;
            const __half* src = &plds[i * 8];
            if (qx0 + 8 <= PW) {
                *(uint4*)dst = *(const uint4*)src;
            } else {
                for (int q = 0; q < 8 && qx0 + q < PW; ++q) dst[q] = src[q];
            }
        }
    }
}

// ---------------- dual depthwise xcorr on MFMA (shift-in-M formulation) ----------
// Single-pass staging: all 4 parity copies written directly from global loads
// (L1-hot neighbor dwords) -- removes the LDS read-back pass + one barrier.
__global__ void __launch_bounds__(256, 4)
xcorr_mfma(const __half* __restrict__ x, const __half* __restrict__ k1,
           const __half* __restrict__ k2,
           float* __restrict__ out1, float* __restrict__ out2) {
    // 4 copies x 8704 B (64 rows x 68 f16, pitch 136 B) at stride 8720 (+16 skew)
    // + klds [2][14][16] f16 (896 B) at 34880. Total 35776 B.
    __shared__ __align__(16) char smem[35776];
    int bc = blockIdx.x, t = threadIdx.x;

    const unsigned* xp = (const unsigned*)(x + (size_t)bc * 3844);   // 62x31 dwords
    for (int idx = t; idx < 64 * 34; idx += 256) {
        int r = idx / 34, i = idx - r * 34;
        unsigned d0 = 0, d1 = 0, d2 = 0;
        if (r < 62) {
            const unsigned* rp = xp + r * 31;
            if (i < 31) d0 = rp[i];
            if (i < 30) d1 = rp[i + 1];
            if (i < 29) d2 = rp[i + 2];
        }
        int ro = r * 136 + i * 4;
        *(unsigned*)(smem + ro) = d0;
        *(unsigned*)(smem +  8720 + ro) = (d0 >> 16) | (d1 << 16);
        *(unsigned*)(smem + 17440 + ro) = d1;
        *(unsigned*)(smem + 26160 + ro) = (d1 >> 16) | (d2 << 16);
    }
    __half* kl = (__half*)(smem + 34880);
    // kernels -> klds [j][row][16] (392 items) + zero the kx=14,15 pad dword/row
    for (int idx = t; idx < 392; idx += 256) {
        int j = idx / 196, r196 = idx - j * 196;
        int kr = r196 / 14, kc = r196 - kr * 14;
        const __half* kg = (j == 0 ? k1 : k2) + (size_t)bc * 196;
        kl[(j * 14 + kr) * 16 + kc] = kg[r196];
    }
    if (t < 28) ((unsigned*)kl)[t * 8 + 7] = 0;
    __syncthreads();

    int lane = t & 63, wid = t >> 6;
    int l15 = lane & 15, l4 = lane >> 4;

    // A fragments: lane's A-row m = l15 -> (j = m>>3, s = m&7); k-slice l4*8+j'
    // -> ky = 2kp + (l4>>1), kx = (l4&1)*8 + j'
    int jm = l15 >> 3, sm = l15 & 7;
    f16x8 zf = (f16x8)(_Float16)0;
    f16x8 af[11];
#pragma unroll
    for (int kp = 0; kp < 11; ++kp) {
        int ky = 2 * kp + (l4 >> 1);
        int rr = ky - sm;
        int rc = min(max(rr, 0), 13);
        f16x8 v = *(const f16x8*)&kl[(jm * 14 + rc) * 16 + (l4 & 1) * 8];
        af[kp] = (rr >= 0 && rr < 14) ? v : zf;
    }

    int cbase = (l4 & 1) * 8 + l15;   // column offset from px0
    int rhalf = l4 >> 1;

    for (int tt = wid; tt < 28; tt += 4) {
        int u = tt % 7, q = tt / 7;
        int py0 = (u < 6) ? u * 8 : 41;
        int px0 = (q < 2) ? q * 16 : (q == 2 ? 32 : 33);

        int c0 = px0 + cbase;
        int p = c0 & 3;
        const char* baddr = smem + p * 8720 + (py0 + rhalf) * 136 + ((c0 - p) >> 2) * 8;

        f32x4 acc = (f32x4)(0.f);
#pragma unroll
        for (int kp = 0; kp < 11; ++kp) {
            union { uint2 u2[2]; f16x8 v; } bu;
            bu.u2[0] = *(const uint2*)(baddr + kp * 272);
            bu.u2[1] = *(const uint2*)(baddr + kp * 272 + 8);
            acc = __builtin_amdgcn_mfma_f32_16x16x32_f16(af[kp], bu.v, acc, 0, 0, 0);
        }

        // C: col = l15 (px), row = l4*4 + r -> (j = row>>3, s = row&7)
        int px = px0 + l15;
#pragma unroll
        for (int r = 0; r < 4; ++r) {
            int m = l4 * 4 + r;
            float* ob = (m >> 3) ? out2 : out1;
            ob[(size_t)bc * 2401 + (size_t)(py0 + (m & 7)) * 49 + px] = acc[r];
        }
    }
}

extern "C" void kernel_launch(void* const* d_in, const int* in_sizes, int n_in,
                              void* d_out, int out_size, void* d_ws, size_t ws_size,
                              hipStream_t stream) {
    const float* img = (const float*)d_in[0];
    const float* t1  = (const float*)d_in[1];
    const float* t2  = (const float*)d_in[2];
    const float* w1  = (const float*)d_in[3];
    const float* b1  = (const float*)d_in[4];
    const float* w2  = (const float*)d_in[5];
    const float* b2  = (const float*)d_in[6];
    float* out = (float*)d_out;

    char* ws = (char*)d_ws;
    __hip_bfloat16* bufA  = (__hip_bfloat16*)ws;                // 66,064,384 B (image)
    __hip_bfloat16* bufA2 = (__hip_bfloat16*)(ws + 33554432);   // template-2 pool1 (3.93MB)
    __hip_bfloat16* w1t  = (__hip_bfloat16*)(ws + 66064384);    // 4,096 B
    __hip_bfloat16* w2h  = (__hip_bfloat16*)(ws + 66068480);    // 147,456 B
    __half* xf = (__half*)(ws + 66215936);                      // 31,490,048
    __half* k1 = (__half*)(ws + 97705984);                      // 1,605,632
    __half* k2 = (__half*)(ws + 99311616);                      // end 100,917,248

    wt_xform_all<<<296, 256, 0, stream>>>(w1, w2, w1t, w2h);

    // Image path
    conv1_mfma<<<dim3(256, 1, 32), 256, 0, stream>>>(img, img, w1t, b1, bufA, bufA,
                                                     256, 256, 127, 127, 16);
    conv2_mfma<<<dim3(128, 1, 32), 256, 0, stream>>>(bufA, bufA, w2h, b2, xf, xf,
                                                     127, 127, 62, 62, 16);

    // Template paths, merged: blockIdx.y selects t1/t2
    conv1_mfma<<<dim3(16, 2, 32), 256, 0, stream>>>(t1, t2, w1t, b1, bufA, bufA2,
                                                    64, 64, 31, 31, 4);
    conv2_mfma<<<dim3(8, 2, 32), 256, 0, stream>>>(bufA, bufA2, w2h, b2, k1, k2,
                                                   31, 31, 14, 14, 4);

    xcorr_mfma<<<4096, 256, 0, stream>>>(xf, k1, k2, out, out + (size_t)9834496);
}